// Round 13
// baseline (439.071 us; speedup 1.0000x reference)
//
#include <hip/hip_runtime.h>
#include <hip/hip_bf16.h>

typedef __bf16 bf16_t;
typedef __bf16 bf16x8 __attribute__((ext_vector_type(8)));
typedef __bf16 bf16x4 __attribute__((ext_vector_type(4)));
typedef float  f32x4  __attribute__((ext_vector_type(4)));

#define S_LEN 4096
#define NH    8
#define DH    64
#define DE    512

// ---------------------------------------------------------------------------
// GEMM tile params (both projection GEMMs)
// ---------------------------------------------------------------------------
#define BM 128
#define BN 128
#define BK 32
#define LDP 40

static __device__ __forceinline__ void stage16_f32(bf16_t* dst, const float* src) {
    const float4 v0 = *reinterpret_cast<const float4*>(src + 0);
    const float4 v1 = *reinterpret_cast<const float4*>(src + 4);
    const float4 v2 = *reinterpret_cast<const float4*>(src + 8);
    const float4 v3 = *reinterpret_cast<const float4*>(src + 12);
    bf16x8 lo, hi;
    lo[0]=(bf16_t)v0.x; lo[1]=(bf16_t)v0.y; lo[2]=(bf16_t)v0.z; lo[3]=(bf16_t)v0.w;
    lo[4]=(bf16_t)v1.x; lo[5]=(bf16_t)v1.y; lo[6]=(bf16_t)v1.z; lo[7]=(bf16_t)v1.w;
    hi[0]=(bf16_t)v2.x; hi[1]=(bf16_t)v2.y; hi[2]=(bf16_t)v2.z; hi[3]=(bf16_t)v2.w;
    hi[4]=(bf16_t)v3.x; hi[5]=(bf16_t)v3.y; hi[6]=(bf16_t)v3.z; hi[7]=(bf16_t)v3.w;
    *reinterpret_cast<bf16x8*>(dst + 0) = lo;
    *reinterpret_cast<bf16x8*>(dst + 8) = hi;
}

// ---------------------------------------------------------------------------
// Kernel 1: qkv = x @ w_in^T + b_in ; scatter to Q [h][s][64], K [h][s][64],
//           V^T [h][64][s]   (all bf16)
// ---------------------------------------------------------------------------
__global__ __launch_bounds__(256) void qkv_gemm(
    const float* __restrict__ X,
    const float* __restrict__ Win,
    const float* __restrict__ bin,
    bf16_t* __restrict__ qw,
    bf16_t* __restrict__ kw,
    bf16_t* __restrict__ vtw)
{
    __shared__ bf16_t As[BM * LDP];
    __shared__ bf16_t Bs[BN * LDP];

    const int tid  = threadIdx.x;
    const int lane = tid & 63;
    const int w    = tid >> 6;
    const int wr   = w >> 1, wc = w & 1;
    const int row0 = blockIdx.y * BM;
    const int col0 = blockIdx.x * BN;

    const int fr = lane & 15;
    const int fo = (lane >> 4) * 8;
    const int cr = (lane >> 4) * 4;

    const int sr = tid >> 1;
    const int sc = (tid & 1) * 16;

    f32x4 acc[4][4] = {};

    for (int k0 = 0; k0 < DE; k0 += BK) {
        stage16_f32(As + sr * LDP + sc, X   + (row0 + sr) * DE + k0 + sc);
        stage16_f32(Bs + sr * LDP + sc, Win + (col0 + sr) * DE + k0 + sc);
        __syncthreads();

        bf16x8 af[4], bf[4];
        #pragma unroll
        for (int m = 0; m < 4; ++m)
            af[m] = *reinterpret_cast<const bf16x8*>(As + (wr * 64 + m * 16 + fr) * LDP + fo);
        #pragma unroll
        for (int n = 0; n < 4; ++n)
            bf[n] = *reinterpret_cast<const bf16x8*>(Bs + (wc * 64 + n * 16 + fr) * LDP + fo);
        #pragma unroll
        for (int m = 0; m < 4; ++m)
            #pragma unroll
            for (int n = 0; n < 4; ++n)
                acc[m][n] = __builtin_amdgcn_mfma_f32_16x16x32_bf16(af[m], bf[n], acc[m][n], 0, 0, 0);
        __syncthreads();
    }

    #pragma unroll
    for (int m = 0; m < 4; ++m) {
        #pragma unroll
        for (int n = 0; n < 4; ++n) {
            const int col = col0 + wc * 64 + n * 16 + fr;
            const float b = bin[col];
            const int part = col >> 9;
            const int cd   = col & 511;
            const int h    = cd >> 6;
            const int d    = cd & 63;
            #pragma unroll
            for (int r = 0; r < 4; ++r) {
                const int row = row0 + wr * 64 + m * 16 + cr + r;
                const float v = acc[m][n][r] + b;
                const bf16_t bv = (bf16_t)v;
                if (part == 0)      qw [(h * S_LEN + row) * DH + d] = bv;
                else if (part == 1) kw [(h * S_LEN + row) * DH + d] = bv;
                else                vtw[(h * DH + d) * S_LEN + row] = bv;
            }
        }
    }
}

// ---------------------------------------------------------------------------
// Kernel 2: attention, softmax over HEADS axis — in-register cross-head den.
//
// One wave owns a 16-q slice and computes ALL 8 heads: the lane holding
// (q,k) holds it at the same register position for every head, so
// den = sum_h e_h is an elementwise in-register add. ZERO barriers in the
// main loop (only the initial Q-stage barrier). e kept as bf16x4
// (e_bf[2][8] = 32 regs — the fix for r2's f32 spill).
//
// Transposed QK^T (r12-verified): D[col=q=fr, row=k=cr+r]. PV needs the
// K=32 A-operand (lane: q=fr, k=fog*8+j) -> built via a wave-private
// slab[2][16][36] (ping-pong by head parity; write->read same wave,
// program order, lgkm only). PV B = V^T from L2 (r7-verified pattern).
//
// Geometry: block = 512 thr = 8 waves = 8 q-slices (128 q), KS=8 ->
// grid 256 = 1 block/CU; kc = blockIdx&7 = XCD id (K/V slice L2-local).
// LDS: Qlds 8h x 128q x 68 (pad) = 139.3 KB + slab 9 KB = 148.5 KB.
// __launch_bounds__(512,2): 128-arch-reg budget (r3-r5 proven); live ~90.
// o[8][4] = 128 acc regs -> 2 waves/SIMD.
// ---------------------------------------------------------------------------
template<int KS>
__global__ __launch_bounds__(512, 2) void attn_kernel(
    const bf16_t* __restrict__ qw,    // [h][s][64]
    const bf16_t* __restrict__ kw,    // [h][s][64]
    const bf16_t* __restrict__ vtw,   // [h][64][s]
    const int*    __restrict__ causal_p,
    bf16_t* __restrict__ part)        // [KS][s][512] partial outputs
{
    constexpr int NSUP = (S_LEN / KS) / 32;    // 32-key super-tiles per wave
    constexpr int KSH  = (KS == 8) ? 3 : (KS == 4) ? 2 : 1;

    __shared__ bf16_t Qlds[NH][128][68];       // 139,264 B
    __shared__ bf16_t slab[8][2][16][36];      //   9,216 B

    const int tid  = threadIdx.x;
    const int lane = tid & 63;
    const int wid  = tid >> 6;                 // q-slice
    const int kc   = blockIdx.x & (KS - 1);    // == XCD id at KS=8
    const int q0   = (blockIdx.x >> KSH) * 128;
    const int kbase = kc * (S_LEN / KS);
    const int causal = causal_p[0];

    const int fr  = lane & 15;
    const int fog = lane >> 4;
    const int fo  = fog * 8;
    const int cr  = fog * 4;
    const int qoff = wid * 16;

    // ---- stage Q (8h x 128q x 64d) into padded LDS, once ----
    #pragma unroll
    for (int it = 0; it < 8; ++it) {
        const int idx = it * 512 + tid;        // 4096 quarter-rows of 32 B
        const int row = idx >> 2;              // (h,q)
        const int qr  = idx & 3;
        const int h   = row >> 7;
        const int q   = row & 127;
        const bf16_t* src = qw + ((size_t)(h * S_LEN) + q0 + q) * DH + qr * 16;
        bf16_t* dst = &Qlds[h][q][qr * 16];
        *reinterpret_cast<bf16x8*>(dst + 0) = *reinterpret_cast<const bf16x8*>(src + 0);
        *reinterpret_cast<bf16x8*>(dst + 8) = *reinterpret_cast<const bf16x8*>(src + 8);
    }
    __syncthreads();   // the ONLY barrier

    f32x4 o[NH][4] = {};   // 128 acc regs

    for (int sup = 0; sup < NSUP; ++sup) {
        const int kg32 = kbase + sup * 32;

        bf16x4 ebf[2][NH];
        f32x4  rdv[2];

        #pragma unroll
        for (int sub = 0; sub < 2; ++sub) {
            const int kg = kg32 + sub * 16;
            f32x4 den = {};
            #pragma unroll
            for (int h = 0; h < NH; ++h) {
                // A = K[k][d]: row k = fr
                const bf16_t* kb = kw + ((size_t)(h * S_LEN) + kg + fr) * DH;
                const bf16x8 ka0 = *reinterpret_cast<const bf16x8*>(kb + fo);
                const bf16x8 ka1 = *reinterpret_cast<const bf16x8*>(kb + 32 + fo);
                // B = Q (col q = fr)
                const bf16_t* qb = &Qlds[h][qoff + fr][0];
                const bf16x8 qb0 = *reinterpret_cast<const bf16x8*>(qb + fo);
                const bf16x8 qb1 = *reinterpret_cast<const bf16x8*>(qb + 32 + fo);
                f32x4 z = {};
                z = __builtin_amdgcn_mfma_f32_16x16x32_bf16(ka0, qb0, z, 0, 0, 0);
                z = __builtin_amdgcn_mfma_f32_16x16x32_bf16(ka1, qb1, z, 0, 0, 0);
                bf16x4 ev;
                #pragma unroll
                for (int r = 0; r < 4; ++r) {
                    float val = __expf(z[r] * 0.125f);
                    if (causal) {
                        if (kg + cr + r > q0 + qoff + fr) val = 0.f;
                    }
                    den[r] += val;
                    ev[r] = (bf16_t)val;
                }
                ebf[sub][h] = ev;
            }
            f32x4 rd;
            #pragma unroll
            for (int r = 0; r < 4; ++r)
                rd[r] = (den[r] > 0.f) ? __builtin_amdgcn_rcpf(den[r]) : 0.f;
            rdv[sub] = rd;
        }

        // ---- w -> wave-private slab (ping-pong by head parity), then PV ----
        auto writeW = [&](int h) {
            #pragma unroll
            for (int sub = 0; sub < 2; ++sub) {
                bf16x4 wv;
                #pragma unroll
                for (int r = 0; r < 4; ++r)
                    wv[r] = (bf16_t)((float)ebf[sub][h][r] * rdv[sub][r]);
                *reinterpret_cast<bf16x4*>(&slab[wid][h & 1][fr][sub * 16 + cr]) = wv;
            }
        };

        writeW(0);
        #pragma unroll
        for (int h = 0; h < NH; ++h) {
            if (h + 1 < NH) writeW(h + 1);
            const bf16x8 pa = *reinterpret_cast<const bf16x8*>(&slab[wid][h & 1][fr][fo]);
            #pragma unroll
            for (int n = 0; n < 4; ++n) {
                const bf16x8 vv = *reinterpret_cast<const bf16x8*>(
                    vtw + ((size_t)(h * DH + n * 16 + fr)) * S_LEN + kg32 + fo);
                o[h][n] = __builtin_amdgcn_mfma_f32_16x16x32_bf16(pa, vv, o[h][n], 0, 0, 0);
            }
        }
    }

    // ---- write partial tile: row = q0+qoff+cr+r, col = h*64+n*16+fr ----
    bf16_t* pp = part + (size_t)kc * (S_LEN * DE);
    #pragma unroll
    for (int h = 0; h < NH; ++h)
        #pragma unroll
        for (int n = 0; n < 4; ++n)
            #pragma unroll
            for (int r = 0; r < 4; ++r)
                pp[(size_t)(q0 + qoff + cr + r) * DE + h * 64 + n * 16 + fr] =
                    (bf16_t)o[h][n][r];
}

// ---------------------------------------------------------------------------
// Kernel 3: out = (sum_kc part_kc) @ w_out^T + b_out   (f32 output)
// ---------------------------------------------------------------------------
template<int KS>
__global__ __launch_bounds__(256) void out_gemm(
    const bf16_t* __restrict__ part,   // [KS][4096][512] bf16
    const float*  __restrict__ Wout,
    const float*  __restrict__ bout,
    float* __restrict__ out)
{
    __shared__ bf16_t As[BM * LDP];
    __shared__ bf16_t Bs[BN * LDP];

    const int tid  = threadIdx.x;
    const int lane = tid & 63;
    const int w    = tid >> 6;
    const int wr   = w >> 1, wc = w & 1;
    const int row0 = blockIdx.y * BM;
    const int col0 = blockIdx.x * BN;

    const int fr = lane & 15;
    const int fo = (lane >> 4) * 8;
    const int cr = (lane >> 4) * 4;

    const int sr = tid >> 1;
    const int sc = (tid & 1) * 16;

    f32x4 acc[4][4] = {};

    for (int k0 = 0; k0 < DE; k0 += BK) {
        {
            const size_t off = (size_t)(row0 + sr) * DE + k0 + sc;
            #pragma unroll
            for (int v = 0; v < 2; ++v) {
                bf16x8 a = *reinterpret_cast<const bf16x8*>(part + off + v * 8);
                #pragma unroll
                for (int p = 1; p < KS; ++p) {
                    bf16x8 b = *reinterpret_cast<const bf16x8*>(
                        part + (size_t)p * (S_LEN * DE) + off + v * 8);
                    #pragma unroll
                    for (int j = 0; j < 8; ++j)
                        a[j] = (bf16_t)((float)a[j] + (float)b[j]);
                }
                *reinterpret_cast<bf16x8*>(As + sr * LDP + sc + v * 8) = a;
            }
        }
        stage16_f32(Bs + sr * LDP + sc, Wout + (col0 + sr) * DE + k0 + sc);
        __syncthreads();

        bf16x8 af[4], bf[4];
        #pragma unroll
        for (int m = 0; m < 4; ++m)
            af[m] = *reinterpret_cast<const bf16x8*>(As + (wr * 64 + m * 16 + fr) * LDP + fo);
        #pragma unroll
        for (int n = 0; n < 4; ++n)
            bf[n] = *reinterpret_cast<const bf16x8*>(Bs + (wc * 64 + n * 16 + fr) * LDP + fo);
        #pragma unroll
        for (int m = 0; m < 4; ++m)
            #pragma unroll
            for (int n = 0; n < 4; ++n)
                acc[m][n] = __builtin_amdgcn_mfma_f32_16x16x32_bf16(af[m], bf[n], acc[m][n], 0, 0, 0);
        __syncthreads();
    }

    #pragma unroll
    for (int m = 0; m < 4; ++m) {
        #pragma unroll
        for (int n = 0; n < 4; ++n) {
            const int col = col0 + wc * 64 + n * 16 + fr;
            const float b = bout[col];
            #pragma unroll
            for (int r = 0; r < 4; ++r) {
                const int row = row0 + wr * 64 + m * 16 + cr + r;
                out[row * DE + col] = acc[m][n][r] + b;
            }
        }
    }
}

// ---------------------------------------------------------------------------
// Launch: needs (3 + KS) * 4 MiB of d_ws. KS=8 confirmed available (r11).
// ---------------------------------------------------------------------------
extern "C" void kernel_launch(void* const* d_in, const int* in_sizes, int n_in,
                              void* d_out, int out_size, void* d_ws, size_t ws_size,
                              hipStream_t stream) {
    const float* x     = (const float*)d_in[0];
    const float* w_in  = (const float*)d_in[1];
    const float* b_in  = (const float*)d_in[2];
    const float* w_out = (const float*)d_in[3];
    const float* b_out = (const float*)d_in[4];
    const int*   causal = (const int*)d_in[5];
    float* out = (float*)d_out;

    const size_t segE = (size_t)NH * S_LEN * DH;      // 2M bf16 elems = 4 MiB
    bf16_t* qw   = (bf16_t*)d_ws;
    bf16_t* kw   = qw  + segE;
    bf16_t* vtw  = kw  + segE;
    bf16_t* part = vtw + segE;

    dim3 g1(3 * DE / BN, S_LEN / BM);   // (12, 32)
    qkv_gemm<<<g1, 256, 0, stream>>>(x, w_in, b_in, qw, kw, vtw);

    dim3 g3(DE / BN, S_LEN / BM);       // (4, 32)

    const size_t segB = segE * sizeof(bf16_t);        // 4 MiB
    if (ws_size >= 11 * segB) {
        // KS=8: grid = 32 q-tiles * 8 = 256 blocks = 1/CU; kc == XCD id
        attn_kernel<8><<<256, 512, 0, stream>>>(qw, kw, vtw, causal, part);
        out_gemm<8><<<g3, 256, 0, stream>>>(part, w_out, b_out, out);
    } else if (ws_size >= 7 * segB) {
        attn_kernel<4><<<128, 512, 0, stream>>>(qw, kw, vtw, causal, part);
        out_gemm<4><<<g3, 256, 0, stream>>>(part, w_out, b_out, out);
    } else {
        attn_kernel<2><<<64, 512, 0, stream>>>(qw, kw, vtw, causal, part);
        out_gemm<2><<<g3, 256, 0, stream>>>(part, w_out, b_out, out);
    }
}

// Round 14
// 192.053 us; speedup vs baseline: 2.2862x; 2.2862x over previous
//
#include <hip/hip_runtime.h>
#include <hip/hip_bf16.h>

typedef __bf16 bf16_t;
typedef __bf16 bf16x8 __attribute__((ext_vector_type(8)));
typedef __bf16 bf16x4 __attribute__((ext_vector_type(4)));
typedef float  f32x4  __attribute__((ext_vector_type(4)));

#define S_LEN 4096
#define NH    8
#define DH    64
#define DE    512

// ---------------------------------------------------------------------------
// GEMM tile params (both projection GEMMs)
// ---------------------------------------------------------------------------
#define BM 128
#define BN 128
#define BK 32
#define LDP 40

static __device__ __forceinline__ void stage16_f32(bf16_t* dst, const float* src) {
    const float4 v0 = *reinterpret_cast<const float4*>(src + 0);
    const float4 v1 = *reinterpret_cast<const float4*>(src + 4);
    const float4 v2 = *reinterpret_cast<const float4*>(src + 8);
    const float4 v3 = *reinterpret_cast<const float4*>(src + 12);
    bf16x8 lo, hi;
    lo[0]=(bf16_t)v0.x; lo[1]=(bf16_t)v0.y; lo[2]=(bf16_t)v0.z; lo[3]=(bf16_t)v0.w;
    lo[4]=(bf16_t)v1.x; lo[5]=(bf16_t)v1.y; lo[6]=(bf16_t)v1.z; lo[7]=(bf16_t)v1.w;
    hi[0]=(bf16_t)v2.x; hi[1]=(bf16_t)v2.y; hi[2]=(bf16_t)v2.z; hi[3]=(bf16_t)v2.w;
    hi[4]=(bf16_t)v3.x; hi[5]=(bf16_t)v3.y; hi[6]=(bf16_t)v3.z; hi[7]=(bf16_t)v3.w;
    *reinterpret_cast<bf16x8*>(dst + 0) = lo;
    *reinterpret_cast<bf16x8*>(dst + 8) = hi;
}

// ---------------------------------------------------------------------------
// Kernel 1: qkv = x @ w_in^T + b_in ; scatter to Q [h][s][64], K [h][s][64],
//           V^T [h][64][s]   (all bf16)
// ---------------------------------------------------------------------------
__global__ __launch_bounds__(256) void qkv_gemm(
    const float* __restrict__ X,
    const float* __restrict__ Win,
    const float* __restrict__ bin,
    bf16_t* __restrict__ qw,
    bf16_t* __restrict__ kw,
    bf16_t* __restrict__ vtw)
{
    __shared__ bf16_t As[BM * LDP];
    __shared__ bf16_t Bs[BN * LDP];

    const int tid  = threadIdx.x;
    const int lane = tid & 63;
    const int w    = tid >> 6;
    const int wr   = w >> 1, wc = w & 1;
    const int row0 = blockIdx.y * BM;
    const int col0 = blockIdx.x * BN;

    const int fr = lane & 15;
    const int fo = (lane >> 4) * 8;
    const int cr = (lane >> 4) * 4;

    const int sr = tid >> 1;
    const int sc = (tid & 1) * 16;

    f32x4 acc[4][4] = {};

    for (int k0 = 0; k0 < DE; k0 += BK) {
        stage16_f32(As + sr * LDP + sc, X   + (row0 + sr) * DE + k0 + sc);
        stage16_f32(Bs + sr * LDP + sc, Win + (col0 + sr) * DE + k0 + sc);
        __syncthreads();

        bf16x8 af[4], bf[4];
        #pragma unroll
        for (int m = 0; m < 4; ++m)
            af[m] = *reinterpret_cast<const bf16x8*>(As + (wr * 64 + m * 16 + fr) * LDP + fo);
        #pragma unroll
        for (int n = 0; n < 4; ++n)
            bf[n] = *reinterpret_cast<const bf16x8*>(Bs + (wc * 64 + n * 16 + fr) * LDP + fo);
        #pragma unroll
        for (int m = 0; m < 4; ++m)
            #pragma unroll
            for (int n = 0; n < 4; ++n)
                acc[m][n] = __builtin_amdgcn_mfma_f32_16x16x32_bf16(af[m], bf[n], acc[m][n], 0, 0, 0);
        __syncthreads();
    }

    #pragma unroll
    for (int m = 0; m < 4; ++m) {
        #pragma unroll
        for (int n = 0; n < 4; ++n) {
            const int col = col0 + wc * 64 + n * 16 + fr;
            const float b = bin[col];
            const int part = col >> 9;
            const int cd   = col & 511;
            const int h    = cd >> 6;
            const int d    = cd & 63;
            #pragma unroll
            for (int r = 0; r < 4; ++r) {
                const int row = row0 + wr * 64 + m * 16 + cr + r;
                const float v = acc[m][n][r] + b;
                const bf16_t bv = (bf16_t)v;
                if (part == 0)      qw [(h * S_LEN + row) * DH + d] = bv;
                else if (part == 1) kw [(h * S_LEN + row) * DH + d] = bv;
                else                vtw[(h * DH + d) * S_LEN + row] = bv;
            }
        }
    }
}

// ---------------------------------------------------------------------------
// Kernel 2: attention, softmax over HEADS axis — r7 structure EXACT
// (the measured optimum: attn = 140 us, spill-free at the backend's hard
// 64-arch-VGPR allocation). 512 threads = 8 waves = 8 heads, QT=32, KS=4,
// 64 KB double-buffered e-LDS, 2 blocks/CU, 2 barriers/tile, unroll-1
// loops, 2-pass normalize, JIT pa/vv loads.
//
// r13 post-mortem: the 4th attempt to hold cross-head state in registers
// spilled (~400 MB scratch traffic). The LDS-exchange design is the right
// trade. Single r14 addition: s_setprio(1) around MFMA clusters — the T5
// technique, measured +4-7% on phase-split attention schedules (null on
// lockstep GEMMs); r7's 3-phase / 16-independent-waves-per-CU schedule is
// the regime where it pays. Zero register/LDS risk.
// ---------------------------------------------------------------------------
template<int QT, int KS>
__global__ __launch_bounds__(512, 4) void attn_kernel(
    const bf16_t* __restrict__ qw,    // [h][s][64]
    const bf16_t* __restrict__ kw,    // [h][s][64]
    const bf16_t* __restrict__ vtw,   // [h][64][s]
    const int*    __restrict__ causal_p,
    bf16_t* __restrict__ part)        // [KS][s][512] partial outputs
{
    constexpr int QF = QT / 16;
    constexpr int NT = (S_LEN / KS) / 64;
    constexpr int KSH = (KS == 4) ? 2 : (KS == 2 ? 1 : 0);

    // [2 buffers][head][q][64 keys], 16B-block XOR swizzle b' = b ^ (q&7)
    __shared__ bf16_t e_lds[2][NH][QT][64];

    const int tid  = threadIdx.x;
    const int lane = tid & 63;
    const int h    = tid >> 6;
    const int kc   = blockIdx.x & (KS - 1);       // key chunk -> XCD-aligned
    const int q0   = (blockIdx.x >> KSH) * QT;
    const int kbase = kc * (S_LEN / KS);
    const int causal = causal_p[0];

    const int fr  = lane & 15;
    const int fog = lane >> 4;
    const int fo  = fog * 8;
    const int cr  = fog * 4;

    // Q fragments (own head): QF row-frags x 2 k-halves (persistent, 16 regs)
    bf16x8 aq[QF][2];
    #pragma unroll
    for (int qf = 0; qf < QF; ++qf) {
        const bf16_t* qb = qw + ((size_t)(h * S_LEN) + q0 + qf * 16 + fr) * DH;
        aq[qf][0] = *reinterpret_cast<const bf16x8*>(qb + fo);
        aq[qf][1] = *reinterpret_cast<const bf16x8*>(qb + 32 + fo);
    }

    f32x4 o[QF][4] = {};   // accumulators (AGPR side of unified file)

    for (int t = 0; t < NT; ++t) {
        const int kg = kbase + t * 64;
        bf16_t* wbuf = &e_lds[t & 1][h][0][0];

        // ---- QK^T + exp -> write e(t) into buf[t&1] ----
        // unroll 1: keep only one kf's K-fragments (8 regs) live at a time
        #pragma unroll 1
        for (int kf = 0; kf < 4; ++kf) {
            const bf16_t* kb = kw + ((size_t)(h * S_LEN) + kg + kf * 16 + fr) * DH;
            const bf16x8 b0 = *reinterpret_cast<const bf16x8*>(kb + fo);
            const bf16x8 b1 = *reinterpret_cast<const bf16x8*>(kb + 32 + fo);
            #pragma unroll
            for (int qf = 0; qf < QF; ++qf) {
                f32x4 z = {};
                __builtin_amdgcn_s_setprio(1);
                z = __builtin_amdgcn_mfma_f32_16x16x32_bf16(aq[qf][0], b0, z, 0, 0, 0);
                z = __builtin_amdgcn_mfma_f32_16x16x32_bf16(aq[qf][1], b1, z, 0, 0, 0);
                __builtin_amdgcn_s_setprio(0);
                #pragma unroll
                for (int r = 0; r < 4; ++r) {
                    float val = __expf(z[r] * 0.125f);
                    if (causal) {
                        if (kg + kf * 16 + fr > q0 + qf * 16 + cr + r) val = 0.f;
                    }
                    const int q = qf * 16 + cr + r;
                    const int k = kf * 16 + fr;
                    const int bp = (k >> 3) ^ (q & 7);
                    wbuf[q * 64 + bp * 8 + (k & 7)] = (bf16_t)val;
                }
            }
        }

        __syncthreads();   // all e(t) writes visible

        // ---- cross-head normalize in place, 2-pass (no eh[] array) ----
        if (tid < QT * 16) {
            const int q  = tid >> 4;
            const int hb = tid & 15;
            const int bp = (hb >> 1) ^ (q & 7);
            bf16_t* base = &e_lds[t & 1][0][0][0] + q * 64 + bp * 8 + (hb & 1) * 4;

            float den0 = 0.f, den1 = 0.f, den2 = 0.f, den3 = 0.f;
            #pragma unroll
            for (int hh = 0; hh < NH; ++hh) {
                const bf16x4 v = *reinterpret_cast<const bf16x4*>(base + hh * (QT * 64));
                den0 += (float)v[0]; den1 += (float)v[1];
                den2 += (float)v[2]; den3 += (float)v[3];
            }
            const float rd0 = (den0 > 0.f) ? __builtin_amdgcn_rcpf(den0) : 0.f;
            const float rd1 = (den1 > 0.f) ? __builtin_amdgcn_rcpf(den1) : 0.f;
            const float rd2 = (den2 > 0.f) ? __builtin_amdgcn_rcpf(den2) : 0.f;
            const float rd3 = (den3 > 0.f) ? __builtin_amdgcn_rcpf(den3) : 0.f;
            #pragma unroll
            for (int hh = 0; hh < NH; ++hh) {
                bf16_t* p = base + hh * (QT * 64);
                const bf16x4 v = *reinterpret_cast<const bf16x4*>(p);
                bf16x4 wv;
                wv[0] = (bf16_t)((float)v[0] * rd0);
                wv[1] = (bf16_t)((float)v[1] * rd1);
                wv[2] = (bf16_t)((float)v[2] * rd2);
                wv[3] = (bf16_t)((float)v[3] * rd3);
                *reinterpret_cast<bf16x4*>(p) = wv;
            }
        }
        __syncthreads();   // w(t) ready

        // ---- PV(t): o += w(t) @ V(t); pa/vv loaded just-in-time ----
        #pragma unroll 1
        for (int c = 0; c < 2; ++c) {
            bf16x8 pa[QF];
            #pragma unroll
            for (int qf = 0; qf < QF; ++qf) {
                const int q  = qf * 16 + fr;
                const int bp = (4 * c + fog) ^ (q & 7);
                pa[qf] = *reinterpret_cast<const bf16x8*>(wbuf + q * 64 + bp * 8);
            }
            #pragma unroll
            for (int n = 0; n < 4; ++n) {
                const bf16x8 vvn = *reinterpret_cast<const bf16x8*>(
                    vtw + ((size_t)(h * DH + n * 16 + fr)) * S_LEN + kg + c * 32 + fo);
                __builtin_amdgcn_s_setprio(1);
                #pragma unroll
                for (int qf = 0; qf < QF; ++qf)
                    o[qf][n] = __builtin_amdgcn_mfma_f32_16x16x32_bf16(pa[qf], vvn, o[qf][n], 0, 0, 0);
                __builtin_amdgcn_s_setprio(0);
            }
        }
        // next tile writes the other buffer; no extra barrier needed
    }

    // write partial output tile [QT][512] bf16
    bf16_t* pp = part + (size_t)kc * (S_LEN * DE);
    #pragma unroll
    for (int qf = 0; qf < QF; ++qf)
        #pragma unroll
        for (int n = 0; n < 4; ++n)
            #pragma unroll
            for (int r = 0; r < 4; ++r)
                pp[(size_t)(q0 + qf * 16 + cr + r) * DE + h * 64 + n * 16 + fr] =
                    (bf16_t)o[qf][n][r];
}

// ---------------------------------------------------------------------------
// Kernel 3: out = (sum_kc part_kc) @ w_out^T + b_out   (f32 output)
// ---------------------------------------------------------------------------
template<int KS>
__global__ __launch_bounds__(256) void out_gemm(
    const bf16_t* __restrict__ part,   // [KS][4096][512] bf16
    const float*  __restrict__ Wout,
    const float*  __restrict__ bout,
    float* __restrict__ out)
{
    __shared__ bf16_t As[BM * LDP];
    __shared__ bf16_t Bs[BN * LDP];

    const int tid  = threadIdx.x;
    const int lane = tid & 63;
    const int w    = tid >> 6;
    const int wr   = w >> 1, wc = w & 1;
    const int row0 = blockIdx.y * BM;
    const int col0 = blockIdx.x * BN;

    const int fr = lane & 15;
    const int fo = (lane >> 4) * 8;
    const int cr = (lane >> 4) * 4;

    const int sr = tid >> 1;
    const int sc = (tid & 1) * 16;

    f32x4 acc[4][4] = {};

    for (int k0 = 0; k0 < DE; k0 += BK) {
        // A staging: sum KS partials (bf16 -> f32 add -> bf16)
        {
            const size_t off = (size_t)(row0 + sr) * DE + k0 + sc;
            #pragma unroll
            for (int v = 0; v < 2; ++v) {
                bf16x8 a = *reinterpret_cast<const bf16x8*>(part + off + v * 8);
                #pragma unroll
                for (int p = 1; p < KS; ++p) {
                    bf16x8 b = *reinterpret_cast<const bf16x8*>(
                        part + (size_t)p * (S_LEN * DE) + off + v * 8);
                    #pragma unroll
                    for (int j = 0; j < 8; ++j)
                        a[j] = (bf16_t)((float)a[j] + (float)b[j]);
                }
                *reinterpret_cast<bf16x8*>(As + sr * LDP + sc + v * 8) = a;
            }
        }
        stage16_f32(Bs + sr * LDP + sc, Wout + (col0 + sr) * DE + k0 + sc);
        __syncthreads();

        bf16x8 af[4], bf[4];
        #pragma unroll
        for (int m = 0; m < 4; ++m)
            af[m] = *reinterpret_cast<const bf16x8*>(As + (wr * 64 + m * 16 + fr) * LDP + fo);
        #pragma unroll
        for (int n = 0; n < 4; ++n)
            bf[n] = *reinterpret_cast<const bf16x8*>(Bs + (wc * 64 + n * 16 + fr) * LDP + fo);
        #pragma unroll
        for (int m = 0; m < 4; ++m)
            #pragma unroll
            for (int n = 0; n < 4; ++n)
                acc[m][n] = __builtin_amdgcn_mfma_f32_16x16x32_bf16(af[m], bf[n], acc[m][n], 0, 0, 0);
        __syncthreads();
    }

    #pragma unroll
    for (int m = 0; m < 4; ++m) {
        #pragma unroll
        for (int n = 0; n < 4; ++n) {
            const int col = col0 + wc * 64 + n * 16 + fr;
            const float b = bout[col];
            #pragma unroll
            for (int r = 0; r < 4; ++r) {
                const int row = row0 + wr * 64 + m * 16 + cr + r;
                out[row * DE + col] = acc[m][n][r] + b;
            }
        }
    }
}

// ---------------------------------------------------------------------------
// Launch: pick key-split factor by available workspace.
//   needs (3 + KS) * 4 MiB of d_ws.
// ---------------------------------------------------------------------------
extern "C" void kernel_launch(void* const* d_in, const int* in_sizes, int n_in,
                              void* d_out, int out_size, void* d_ws, size_t ws_size,
                              hipStream_t stream) {
    const float* x     = (const float*)d_in[0];
    const float* w_in  = (const float*)d_in[1];
    const float* b_in  = (const float*)d_in[2];
    const float* w_out = (const float*)d_in[3];
    const float* b_out = (const float*)d_in[4];
    const int*   causal = (const int*)d_in[5];
    float* out = (float*)d_out;

    const size_t segE = (size_t)NH * S_LEN * DH;      // 2M bf16 elems = 4 MiB
    bf16_t* qw   = (bf16_t*)d_ws;
    bf16_t* kw   = qw  + segE;
    bf16_t* vtw  = kw  + segE;
    bf16_t* part = vtw + segE;

    dim3 g1(3 * DE / BN, S_LEN / BM);   // (12, 32)
    qkv_gemm<<<g1, 256, 0, stream>>>(x, w_in, b_in, qw, kw, vtw);

    dim3 g3(DE / BN, S_LEN / BM);       // (4, 32)

    const size_t segB = segE * sizeof(bf16_t);        // 4 MiB
    if (ws_size >= 7 * segB) {
        // QT=32, KS=4: grid = 4 * 128 = 512 blocks -> 2 blocks/CU
        attn_kernel<32, 4><<<512, 512, 0, stream>>>(qw, kw, vtw, causal, part);
        out_gemm<4><<<g3, 256, 0, stream>>>(part, w_out, b_out, out);
    } else if (ws_size >= 5 * segB) {
        attn_kernel<32, 2><<<256, 512, 0, stream>>>(qw, kw, vtw, causal, part);
        out_gemm<2><<<g3, 256, 0, stream>>>(part, w_out, b_out, out);
    } else {
        attn_kernel<16, 1><<<256, 512, 0, stream>>>(qw, kw, vtw, causal, part);
        out_gemm<1><<<g3, 256, 0, stream>>>(part, w_out, b_out, out);
    }
}

// Round 15
// 185.463 us; speedup vs baseline: 2.3674x; 1.0355x over previous
//
#include <hip/hip_runtime.h>
#include <hip/hip_bf16.h>

typedef __bf16 bf16_t;
typedef __bf16 bf16x8 __attribute__((ext_vector_type(8)));
typedef __bf16 bf16x4 __attribute__((ext_vector_type(4)));
typedef float  f32x4  __attribute__((ext_vector_type(4)));

#define S_LEN 4096
#define NH    8
#define DH    64
#define DE    512

// ---------------------------------------------------------------------------
// GEMM tile params
// ---------------------------------------------------------------------------
#define BM 128
#define BN 128
#define BK 32
#define LDP 40

static __device__ __forceinline__ void stage16_f32(bf16_t* dst, const float* src) {
    const float4 v0 = *reinterpret_cast<const float4*>(src + 0);
    const float4 v1 = *reinterpret_cast<const float4*>(src + 4);
    const float4 v2 = *reinterpret_cast<const float4*>(src + 8);
    const float4 v3 = *reinterpret_cast<const float4*>(src + 12);
    bf16x8 lo, hi;
    lo[0]=(bf16_t)v0.x; lo[1]=(bf16_t)v0.y; lo[2]=(bf16_t)v0.z; lo[3]=(bf16_t)v0.w;
    lo[4]=(bf16_t)v1.x; lo[5]=(bf16_t)v1.y; lo[6]=(bf16_t)v1.z; lo[7]=(bf16_t)v1.w;
    hi[0]=(bf16_t)v2.x; hi[1]=(bf16_t)v2.y; hi[2]=(bf16_t)v2.z; hi[3]=(bf16_t)v2.w;
    hi[4]=(bf16_t)v3.x; hi[5]=(bf16_t)v3.y; hi[6]=(bf16_t)v3.z; hi[7]=(bf16_t)v3.w;
    *reinterpret_cast<bf16x8*>(dst + 0) = lo;
    *reinterpret_cast<bf16x8*>(dst + 8) = hi;
}

// global -> LDS direct DMA, 16 B per lane. LDS dest must be wave-uniform
// base (HW adds lane*16); global src is per-lane.
typedef __attribute__((address_space(3))) void lds_void;
typedef const __attribute__((address_space(1))) void g_void;
static __device__ __forceinline__ void gload_lds16(const void* g, void* l) {
    __builtin_amdgcn_global_load_lds((g_void*)g, (lds_void*)l, 16, 0, 0);
}

// ---------------------------------------------------------------------------
// Kernel 0: convert x, w_in, w_out (f32) -> bf16 workspace copies, one pass.
// 393216 threads x 8 elems. Boundaries are multiples of 8.
// ---------------------------------------------------------------------------
__global__ __launch_bounds__(256) void cvt_inputs(
    const float* __restrict__ x,      // 2,097,152
    const float* __restrict__ w_in,   //   786,432
    const float* __restrict__ w_out,  //   262,144
    bf16_t* __restrict__ xb,
    bf16_t* __restrict__ wib,
    bf16_t* __restrict__ wob)
{
    const size_t e0 = ((size_t)blockIdx.x * blockDim.x + threadIdx.x) * 8;
    const float* src;
    bf16_t* dst;
    size_t off;
    if (e0 < 2097152)      { src = x;     dst = xb;  off = e0; }
    else if (e0 < 2883584) { src = w_in;  dst = wib; off = e0 - 2097152; }
    else                   { src = w_out; dst = wob; off = e0 - 2883584; }
    const float4 a = *reinterpret_cast<const float4*>(src + off);
    const float4 b = *reinterpret_cast<const float4*>(src + off + 4);
    bf16x8 v;
    v[0]=(bf16_t)a.x; v[1]=(bf16_t)a.y; v[2]=(bf16_t)a.z; v[3]=(bf16_t)a.w;
    v[4]=(bf16_t)b.x; v[5]=(bf16_t)b.y; v[6]=(bf16_t)b.z; v[7]=(bf16_t)b.w;
    *reinterpret_cast<bf16x8*>(dst + off) = v;
}

// ---------------------------------------------------------------------------
// Kernel 1 (new): qkv = x @ w_in^T + b_in from BF16 inputs via
// global_load_lds (m97 structure: linear 8 KB LDS tiles, width-16 DMA).
// Per K-iter per wave: 2 A-chunks + 2 B-chunks of 1 KB. Chunk c covers
// rows c*16..c*16+15 (lane: row = c*16 + (lane>>2), col = (lane&3)*8).
// Scatter epilogue unchanged: Q [h][s][64], K [h][s][64], V^T [h][64][s].
// ---------------------------------------------------------------------------
__global__ __launch_bounds__(256) void qkv_gemm_bf16(
    const bf16_t* __restrict__ Xb,    // [4096][512]
    const bf16_t* __restrict__ Wb,    // [1536][512]
    const float*  __restrict__ bin,
    bf16_t* __restrict__ qw,
    bf16_t* __restrict__ kw,
    bf16_t* __restrict__ vtw)
{
    __shared__ bf16_t As[BM * BK];    // linear, 8 KB (gload_lds needs no pad)
    __shared__ bf16_t Bs[BN * BK];

    const int tid  = threadIdx.x;
    const int lane = tid & 63;
    const int w    = tid >> 6;
    const int wr   = w >> 1, wc = w & 1;
    const int row0 = blockIdx.y * BM;
    const int col0 = blockIdx.x * BN;

    const int fr = lane & 15;
    const int fo = (lane >> 4) * 8;
    const int cr = (lane >> 4) * 4;

    const int lr = lane >> 2;          // row within chunk (0..15)
    const int lc = (lane & 3) * 8;     // col offset in elems

    f32x4 acc[4][4] = {};

    for (int k0 = 0; k0 < DE; k0 += BK) {
        #pragma unroll
        for (int i = 0; i < 2; ++i) {
            const int c = w * 2 + i;               // chunk 0..7 (wave-uniform)
            const int r = c * 16 + lr;
            gload_lds16(Xb + (size_t)(row0 + r) * DE + k0 + lc, As + c * 512);
            gload_lds16(Wb + (size_t)(col0 + r) * DE + k0 + lc, Bs + c * 512);
        }
        __syncthreads();   // drains vmcnt (incl. LDS-DMA) + lgkm

        bf16x8 af[4], bf[4];
        #pragma unroll
        for (int m = 0; m < 4; ++m)
            af[m] = *reinterpret_cast<const bf16x8*>(As + (wr * 64 + m * 16 + fr) * BK + fo);
        #pragma unroll
        for (int n = 0; n < 4; ++n)
            bf[n] = *reinterpret_cast<const bf16x8*>(Bs + (wc * 64 + n * 16 + fr) * BK + fo);
        #pragma unroll
        for (int m = 0; m < 4; ++m)
            #pragma unroll
            for (int n = 0; n < 4; ++n)
                acc[m][n] = __builtin_amdgcn_mfma_f32_16x16x32_bf16(af[m], bf[n], acc[m][n], 0, 0, 0);
        __syncthreads();
    }

    #pragma unroll
    for (int m = 0; m < 4; ++m) {
        #pragma unroll
        for (int n = 0; n < 4; ++n) {
            const int col = col0 + wc * 64 + n * 16 + fr;
            const float b = bin[col];
            const int part = col >> 9;
            const int cd   = col & 511;
            const int h    = cd >> 6;
            const int d    = cd & 63;
            #pragma unroll
            for (int r = 0; r < 4; ++r) {
                const int row = row0 + wr * 64 + m * 16 + cr + r;
                const float v = acc[m][n][r] + b;
                const bf16_t bv = (bf16_t)v;
                if (part == 0)      qw [(h * S_LEN + row) * DH + d] = bv;
                else if (part == 1) kw [(h * S_LEN + row) * DH + d] = bv;
                else                vtw[(h * DH + d) * S_LEN + row] = bv;
            }
        }
    }
}

// ---------------------------------------------------------------------------
// Kernel 1 (fallback, f32 inputs): original staging path
// ---------------------------------------------------------------------------
__global__ __launch_bounds__(256) void qkv_gemm(
    const float* __restrict__ X,
    const float* __restrict__ Win,
    const float* __restrict__ bin,
    bf16_t* __restrict__ qw,
    bf16_t* __restrict__ kw,
    bf16_t* __restrict__ vtw)
{
    __shared__ bf16_t As[BM * LDP];
    __shared__ bf16_t Bs[BN * LDP];

    const int tid  = threadIdx.x;
    const int lane = tid & 63;
    const int w    = tid >> 6;
    const int wr   = w >> 1, wc = w & 1;
    const int row0 = blockIdx.y * BM;
    const int col0 = blockIdx.x * BN;

    const int fr = lane & 15;
    const int fo = (lane >> 4) * 8;
    const int cr = (lane >> 4) * 4;

    const int sr = tid >> 1;
    const int sc = (tid & 1) * 16;

    f32x4 acc[4][4] = {};

    for (int k0 = 0; k0 < DE; k0 += BK) {
        stage16_f32(As + sr * LDP + sc, X   + (row0 + sr) * DE + k0 + sc);
        stage16_f32(Bs + sr * LDP + sc, Win + (col0 + sr) * DE + k0 + sc);
        __syncthreads();

        bf16x8 af[4], bf[4];
        #pragma unroll
        for (int m = 0; m < 4; ++m)
            af[m] = *reinterpret_cast<const bf16x8*>(As + (wr * 64 + m * 16 + fr) * LDP + fo);
        #pragma unroll
        for (int n = 0; n < 4; ++n)
            bf[n] = *reinterpret_cast<const bf16x8*>(Bs + (wc * 64 + n * 16 + fr) * LDP + fo);
        #pragma unroll
        for (int m = 0; m < 4; ++m)
            #pragma unroll
            for (int n = 0; n < 4; ++n)
                acc[m][n] = __builtin_amdgcn_mfma_f32_16x16x32_bf16(af[m], bf[n], acc[m][n], 0, 0, 0);
        __syncthreads();
    }

    #pragma unroll
    for (int m = 0; m < 4; ++m) {
        #pragma unroll
        for (int n = 0; n < 4; ++n) {
            const int col = col0 + wc * 64 + n * 16 + fr;
            const float b = bin[col];
            const int part = col >> 9;
            const int cd   = col & 511;
            const int h    = cd >> 6;
            const int d    = cd & 63;
            #pragma unroll
            for (int r = 0; r < 4; ++r) {
                const int row = row0 + wr * 64 + m * 16 + cr + r;
                const float v = acc[m][n][r] + b;
                const bf16_t bv = (bf16_t)v;
                if (part == 0)      qw [(h * S_LEN + row) * DH + d] = bv;
                else if (part == 1) kw [(h * S_LEN + row) * DH + d] = bv;
                else                vtw[(h * DH + d) * S_LEN + row] = bv;
            }
        }
    }
}

// ---------------------------------------------------------------------------
// Kernel 2: attention, softmax over HEADS axis — r7/r14 structure EXACT
// (measured optimum: 139 us, spill-free at the backend's hard 64-arch-VGPR
// allocation). UNCHANGED this round.
// ---------------------------------------------------------------------------
template<int QT, int KS>
__global__ __launch_bounds__(512, 4) void attn_kernel(
    const bf16_t* __restrict__ qw,    // [h][s][64]
    const bf16_t* __restrict__ kw,    // [h][s][64]
    const bf16_t* __restrict__ vtw,   // [h][64][s]
    const int*    __restrict__ causal_p,
    bf16_t* __restrict__ part)        // [KS][s][512] partial outputs
{
    constexpr int QF = QT / 16;
    constexpr int NT = (S_LEN / KS) / 64;
    constexpr int KSH = (KS == 4) ? 2 : (KS == 2 ? 1 : 0);

    __shared__ bf16_t e_lds[2][NH][QT][64];

    const int tid  = threadIdx.x;
    const int lane = tid & 63;
    const int h    = tid >> 6;
    const int kc   = blockIdx.x & (KS - 1);
    const int q0   = (blockIdx.x >> KSH) * QT;
    const int kbase = kc * (S_LEN / KS);
    const int causal = causal_p[0];

    const int fr  = lane & 15;
    const int fog = lane >> 4;
    const int fo  = fog * 8;
    const int cr  = fog * 4;

    bf16x8 aq[QF][2];
    #pragma unroll
    for (int qf = 0; qf < QF; ++qf) {
        const bf16_t* qb = qw + ((size_t)(h * S_LEN) + q0 + qf * 16 + fr) * DH;
        aq[qf][0] = *reinterpret_cast<const bf16x8*>(qb + fo);
        aq[qf][1] = *reinterpret_cast<const bf16x8*>(qb + 32 + fo);
    }

    f32x4 o[QF][4] = {};

    for (int t = 0; t < NT; ++t) {
        const int kg = kbase + t * 64;
        bf16_t* wbuf = &e_lds[t & 1][h][0][0];

        #pragma unroll 1
        for (int kf = 0; kf < 4; ++kf) {
            const bf16_t* kb = kw + ((size_t)(h * S_LEN) + kg + kf * 16 + fr) * DH;
            const bf16x8 b0 = *reinterpret_cast<const bf16x8*>(kb + fo);
            const bf16x8 b1 = *reinterpret_cast<const bf16x8*>(kb + 32 + fo);
            #pragma unroll
            for (int qf = 0; qf < QF; ++qf) {
                f32x4 z = {};
                __builtin_amdgcn_s_setprio(1);
                z = __builtin_amdgcn_mfma_f32_16x16x32_bf16(aq[qf][0], b0, z, 0, 0, 0);
                z = __builtin_amdgcn_mfma_f32_16x16x32_bf16(aq[qf][1], b1, z, 0, 0, 0);
                __builtin_amdgcn_s_setprio(0);
                #pragma unroll
                for (int r = 0; r < 4; ++r) {
                    float val = __expf(z[r] * 0.125f);
                    if (causal) {
                        if (kg + kf * 16 + fr > q0 + qf * 16 + cr + r) val = 0.f;
                    }
                    const int q = qf * 16 + cr + r;
                    const int k = kf * 16 + fr;
                    const int bp = (k >> 3) ^ (q & 7);
                    wbuf[q * 64 + bp * 8 + (k & 7)] = (bf16_t)val;
                }
            }
        }

        __syncthreads();

        if (tid < QT * 16) {
            const int q  = tid >> 4;
            const int hb = tid & 15;
            const int bp = (hb >> 1) ^ (q & 7);
            bf16_t* base = &e_lds[t & 1][0][0][0] + q * 64 + bp * 8 + (hb & 1) * 4;

            float den0 = 0.f, den1 = 0.f, den2 = 0.f, den3 = 0.f;
            #pragma unroll
            for (int hh = 0; hh < NH; ++hh) {
                const bf16x4 v = *reinterpret_cast<const bf16x4*>(base + hh * (QT * 64));
                den0 += (float)v[0]; den1 += (float)v[1];
                den2 += (float)v[2]; den3 += (float)v[3];
            }
            const float rd0 = (den0 > 0.f) ? __builtin_amdgcn_rcpf(den0) : 0.f;
            const float rd1 = (den1 > 0.f) ? __builtin_amdgcn_rcpf(den1) : 0.f;
            const float rd2 = (den2 > 0.f) ? __builtin_amdgcn_rcpf(den2) : 0.f;
            const float rd3 = (den3 > 0.f) ? __builtin_amdgcn_rcpf(den3) : 0.f;
            #pragma unroll
            for (int hh = 0; hh < NH; ++hh) {
                bf16_t* p = base + hh * (QT * 64);
                const bf16x4 v = *reinterpret_cast<const bf16x4*>(p);
                bf16x4 wv;
                wv[0] = (bf16_t)((float)v[0] * rd0);
                wv[1] = (bf16_t)((float)v[1] * rd1);
                wv[2] = (bf16_t)((float)v[2] * rd2);
                wv[3] = (bf16_t)((float)v[3] * rd3);
                *reinterpret_cast<bf16x4*>(p) = wv;
            }
        }
        __syncthreads();

        #pragma unroll 1
        for (int c = 0; c < 2; ++c) {
            bf16x8 pa[QF];
            #pragma unroll
            for (int qf = 0; qf < QF; ++qf) {
                const int q  = qf * 16 + fr;
                const int bp = (4 * c + fog) ^ (q & 7);
                pa[qf] = *reinterpret_cast<const bf16x8*>(wbuf + q * 64 + bp * 8);
            }
            #pragma unroll
            for (int n = 0; n < 4; ++n) {
                const bf16x8 vvn = *reinterpret_cast<const bf16x8*>(
                    vtw + ((size_t)(h * DH + n * 16 + fr)) * S_LEN + kg + c * 32 + fo);
                __builtin_amdgcn_s_setprio(1);
                #pragma unroll
                for (int qf = 0; qf < QF; ++qf)
                    o[qf][n] = __builtin_amdgcn_mfma_f32_16x16x32_bf16(pa[qf], vvn, o[qf][n], 0, 0, 0);
                __builtin_amdgcn_s_setprio(0);
            }
        }
    }

    bf16_t* pp = part + (size_t)kc * (S_LEN * DE);
    #pragma unroll
    for (int qf = 0; qf < QF; ++qf)
        #pragma unroll
        for (int n = 0; n < 4; ++n)
            #pragma unroll
            for (int r = 0; r < 4; ++r)
                pp[(size_t)(q0 + qf * 16 + cr + r) * DE + h * 64 + n * 16 + fr] =
                    (bf16_t)o[qf][n][r];
}

// ---------------------------------------------------------------------------
// Kernel 3: out = (sum_kc part_kc) @ w_out^T + b_out   (f32 output)
// BF16B: B staged from pre-converted bf16 w_out (no per-iter converts).
// ---------------------------------------------------------------------------
template<int KS, bool BF16B>
__global__ __launch_bounds__(256) void out_gemm(
    const bf16_t* __restrict__ part,   // [KS][4096][512] bf16
    const float*  __restrict__ Wout,   // f32 (fallback path)
    const bf16_t* __restrict__ Woutb,  // bf16 (fast path)
    const float*  __restrict__ bout,
    float* __restrict__ out)
{
    __shared__ bf16_t As[BM * LDP];
    __shared__ bf16_t Bs[BN * LDP];

    const int tid  = threadIdx.x;
    const int lane = tid & 63;
    const int w    = tid >> 6;
    const int wr   = w >> 1, wc = w & 1;
    const int row0 = blockIdx.y * BM;
    const int col0 = blockIdx.x * BN;

    const int fr = lane & 15;
    const int fo = (lane >> 4) * 8;
    const int cr = (lane >> 4) * 4;

    const int sr = tid >> 1;
    const int sc = (tid & 1) * 16;

    f32x4 acc[4][4] = {};

    for (int k0 = 0; k0 < DE; k0 += BK) {
        {
            const size_t off = (size_t)(row0 + sr) * DE + k0 + sc;
            #pragma unroll
            for (int v = 0; v < 2; ++v) {
                bf16x8 a = *reinterpret_cast<const bf16x8*>(part + off + v * 8);
                #pragma unroll
                for (int p = 1; p < KS; ++p) {
                    bf16x8 b = *reinterpret_cast<const bf16x8*>(
                        part + (size_t)p * (S_LEN * DE) + off + v * 8);
                    #pragma unroll
                    for (int j = 0; j < 8; ++j)
                        a[j] = (bf16_t)((float)a[j] + (float)b[j]);
                }
                *reinterpret_cast<bf16x8*>(As + sr * LDP + sc + v * 8) = a;
            }
        }
        if (BF16B) {
            const bf16_t* src = Woutb + (size_t)(col0 + sr) * DE + k0 + sc;
            *reinterpret_cast<bf16x8*>(Bs + sr * LDP + sc + 0) =
                *reinterpret_cast<const bf16x8*>(src + 0);
            *reinterpret_cast<bf16x8*>(Bs + sr * LDP + sc + 8) =
                *reinterpret_cast<const bf16x8*>(src + 8);
        } else {
            stage16_f32(Bs + sr * LDP + sc, Wout + (col0 + sr) * DE + k0 + sc);
        }
        __syncthreads();

        bf16x8 af[4], bf[4];
        #pragma unroll
        for (int m = 0; m < 4; ++m)
            af[m] = *reinterpret_cast<const bf16x8*>(As + (wr * 64 + m * 16 + fr) * LDP + fo);
        #pragma unroll
        for (int n = 0; n < 4; ++n)
            bf[n] = *reinterpret_cast<const bf16x8*>(Bs + (wc * 64 + n * 16 + fr) * LDP + fo);
        #pragma unroll
        for (int m = 0; m < 4; ++m)
            #pragma unroll
            for (int n = 0; n < 4; ++n)
                acc[m][n] = __builtin_amdgcn_mfma_f32_16x16x32_bf16(af[m], bf[n], acc[m][n], 0, 0, 0);
        __syncthreads();
    }

    #pragma unroll
    for (int m = 0; m < 4; ++m) {
        #pragma unroll
        for (int n = 0; n < 4; ++n) {
            const int col = col0 + wc * 64 + n * 16 + fr;
            const float b = bout[col];
            #pragma unroll
            for (int r = 0; r < 4; ++r) {
                const int row = row0 + wr * 64 + m * 16 + cr + r;
                out[row * DE + col] = acc[m][n][r] + b;
            }
        }
    }
}

// ---------------------------------------------------------------------------
// Launch
// ---------------------------------------------------------------------------
extern "C" void kernel_launch(void* const* d_in, const int* in_sizes, int n_in,
                              void* d_out, int out_size, void* d_ws, size_t ws_size,
                              hipStream_t stream) {
    const float* x     = (const float*)d_in[0];
    const float* w_in  = (const float*)d_in[1];
    const float* b_in  = (const float*)d_in[2];
    const float* w_out = (const float*)d_in[3];
    const float* b_out = (const float*)d_in[4];
    const int*   causal = (const int*)d_in[5];
    float* out = (float*)d_out;

    const size_t segE = (size_t)NH * S_LEN * DH;      // 2,097,152 elems = 4 MiB
    bf16_t* qw   = (bf16_t*)d_ws;
    bf16_t* kw   = qw  + segE;
    bf16_t* vtw  = kw  + segE;
    bf16_t* part = vtw + segE;                        // KS=4 -> 4 segs

    dim3 g1(3 * DE / BN, S_LEN / BM);   // (12, 32)
    dim3 g3(DE / BN, S_LEN / BM);       // (4, 32)

    // fast path needs: 7 segs + xb(1 seg) + wib(786432) + wob(262144)
    const size_t needE = 8 * segE + 786432 + 262144;  // 17,825,792 elems
    const size_t segB  = segE * sizeof(bf16_t);

    if (ws_size >= needE * sizeof(bf16_t)) {
        bf16_t* xb  = part + 4 * segE;
        bf16_t* wib = xb + segE;
        bf16_t* wob = wib + 786432;

        cvt_inputs<<<1536, 256, 0, stream>>>(x, w_in, w_out, xb, wib, wob);
        qkv_gemm_bf16<<<g1, 256, 0, stream>>>(xb, wib, b_in, qw, kw, vtw);
        attn_kernel<32, 4><<<512, 512, 0, stream>>>(qw, kw, vtw, causal, part);
        out_gemm<4, true><<<g3, 256, 0, stream>>>(part, w_out, wob, b_out, out);
    } else if (ws_size >= 7 * segB) {
        qkv_gemm<<<g1, 256, 0, stream>>>(x, w_in, b_in, qw, kw, vtw);
        attn_kernel<32, 4><<<512, 512, 0, stream>>>(qw, kw, vtw, causal, part);
        out_gemm<4, false><<<g3, 256, 0, stream>>>(part, w_out, nullptr, b_out, out);
    } else if (ws_size >= 5 * segB) {
        qkv_gemm<<<g1, 256, 0, stream>>>(x, w_in, b_in, qw, kw, vtw);
        attn_kernel<32, 2><<<256, 512, 0, stream>>>(qw, kw, vtw, causal, part);
        out_gemm<2, false><<<g3, 256, 0, stream>>>(part, w_out, nullptr, b_out, out);
    } else {
        qkv_gemm<<<g1, 256, 0, stream>>>(x, w_in, b_in, qw, kw, vtw);
        attn_kernel<16, 1><<<256, 512, 0, stream>>>(qw, kw, vtw, causal, part);
        out_gemm<1, false><<<g3, 256, 0, stream>>>(part, w_out, nullptr, b_out, out);
    }
}